// Round 16
// baseline (114.118 us; speedup 1.0000x reference)
//
#include <hip/hip_runtime.h>
#include <hip/hip_bf16.h>

#define B_   2048
#define N_   1024
#define BETA 0.001f
#define VAR_MIN 1e-7f

#define NIT  16               // 16 iters x 16 pts = 256 pts per wave

typedef __attribute__((ext_vector_type(8))) short  bf16x8;
typedef __attribute__((ext_vector_type(4))) float  f32x4;
typedef __attribute__((ext_vector_type(4))) unsigned int u32x4;

__device__ __forceinline__ unsigned short f2bf_u(float x) {
    __hip_bfloat16 h = __float2bfloat16(x);   // RNE
    return __builtin_bit_cast(unsigned short, h);
}
__device__ __forceinline__ unsigned int cvtpk(float lo, float hi) {
    unsigned int r;
    asm("v_cvt_pk_bf16_f32 %0, %1, %2" : "=v"(r) : "v"(lo), "v"(hi));
    return r;
}
// hot-path softplus: 2 HW transcendentals. x<-16: 1+e^x -> 1 -> sp=0 -> VAR_MIN
// clamp, matching the reference's max(var, VAR_MIN).
__device__ __forceinline__ float softplus_cheap(float x) {
    float sp = __logf(1.f + __expf(x));
    return x > 15.f ? x : sp;
}
__device__ __forceinline__ float rcp_fast(float x) {
    return __builtin_amdgcn_rcpf(x);
}
__device__ __forceinline__ float softplus_ref(float x) {
    return x > 20.f ? x : log1pf(expf(x));
}
__device__ __forceinline__ float iv_of(float x) {
    return rcp_fast(fmaxf(softplus_cheap(x), VAR_MIN));
}

// pi(k): contraction-position permutation (verified absmax 0.0 in R4-R15)
__device__ __forceinline__ int kperm(int k) {
    return 4 * (k >> 3) + (k & 3) + 16 * ((k >> 2) & 1);
}

// A-frag weight prep; head rows interleaved [mu,mu,v,v] per lane-group (R13)
extern "C" __global__ void hib_prep(const float* __restrict__ W1,
                                    const float* __restrict__ W2,
                                    const float* __restrict__ Wmu,
                                    const float* __restrict__ Wv,
                                    unsigned short* __restrict__ wf)
{
    const int l = threadIdx.x;         // 0..63
    const int r = l & 15, kb = l >> 4;
    const int kbr = r >> 2, ri = r & 3;
#pragma unroll
    for (int j = 0; j < 8; j++) {
        const int k1 = kb * 8 + j;
        const int kp = kperm(k1);
        wf[(0 * 64 + l) * 8 + j] = f2bf_u(W1[k1 * 32 + r]);
        wf[(1 * 64 + l) * 8 + j] = f2bf_u(W1[k1 * 32 + 16 + r]);
        wf[(2 * 64 + l) * 8 + j] = f2bf_u(W2[kp * 32 + r]);
        wf[(3 * 64 + l) * 8 + j] = f2bf_u(W2[kp * 32 + 16 + r]);
        wf[(4 * 64 + l) * 8 + j] = f2bf_u(ri < 2 ? Wmu[kp * 8 + 2 * kbr + ri]
                                                 : Wv[kp * 8 + 2 * kbr + (ri - 2)]);
    }
}

__device__ __forceinline__ bf16x8 pack_relu(f32x4 a, f32x4 b) {
    u32x4 w;
    w[0] = cvtpk(fmaxf(a[0], 0.f), fmaxf(a[1], 0.f));
    w[1] = cvtpk(fmaxf(a[2], 0.f), fmaxf(a[3], 0.f));
    w[2] = cvtpk(fmaxf(b[0], 0.f), fmaxf(b[1], 0.f));
    w[3] = cvtpk(fmaxf(b[2], 0.f), fmaxf(b[3], 0.f));
    return __builtin_bit_cast(bf16x8, w);
}

__device__ __forceinline__ void red16(f32x4& v) {
#pragma unroll
    for (int off = 8; off; off >>= 1) {
        v[0] += __shfl_down(v[0], off);
        v[1] += __shfl_down(v[1], off);
        v[2] += __shfl_down(v[2], off);
        v[3] += __shfl_down(v[3], off);
    }
}

// wave-private stage: 32 rows x 16 pts x 2ch (4KB) for iteration `it`.
// 4 instrs; instr q: 8 rows x 128B, per-lane global addr (row l>>3, 16B chunk
// l&7), wave-uniform LDS dest (linear lane*16B = [row][ptpair] layout).
__device__ __forceinline__ void stage_wp(const float* __restrict__ bbase,
                                         float* __restrict__ buf,
                                         int it, int wid, int l)
{
    const int lrow = l >> 3, lcol = (l & 7) * 4;   // floats
    const int colbase = (wid * 256 + it * 16) * 2; // floats within a row
#pragma unroll
    for (int q = 0; q < 4; ++q) {
        const int row = q * 8 + lrow;
        const float* gs = bbase + (size_t)row * (2 * N_) + colbase + lcol;
        __builtin_amdgcn_global_load_lds(
            (const __attribute__((address_space(1))) unsigned int*)gs,
            (__attribute__((address_space(3))) unsigned int*)&buf[q * 8 * 32],
            16, 0, 0);
    }
}

__global__ void __launch_bounds__(256, 3)
hib_mfma(const float* __restrict__ batch,
         const int* __restrict__ labels,
         const float* __restrict__ eps1, const float* __restrict__ eps2,
         const unsigned short* __restrict__ wf,
         const float* __restrict__ b1, const float* __restrict__ b2,
         const float* __restrict__ bmu, const float* __restrict__ bv,
         const float* __restrict__ sw, const float* __restrict__ sb,
         float* __restrict__ out)
{
    __shared__ float lds[4][3][32 * 32];   // [wave][buf][row*32] = 48KB
    __shared__ float sacc[32];

    const int tid = threadIdx.x;
    const int b   = blockIdx.x;
    const int wid = tid >> 6, l = tid & 63;
    const int c   = l & 15, kb = l >> 4;

    if (tid < 32) sacc[tid] = 0.f;

    // weight A-frags, register-resident
    const bf16x8* wfv = (const bf16x8*)wf;
    const bf16x8 A1a = wfv[0 * 64 + l], A1b = wfv[1 * 64 + l];
    const bf16x8 A2a = wfv[2 * 64 + l], A2b = wfv[3 * 64 + l];
    const bf16x8 Ahd = wfv[4 * 64 + l];

    const int r4 = 4 * kb;
    const int z2 = 2 * kb;          // interleaved head: this group's z-pair
    f32x4 c1a, c1b, c2a, c2b, chd;
    c1a[0] = b1[r4];      c1a[1] = b1[r4 + 1];      c1a[2] = b1[r4 + 2];      c1a[3] = b1[r4 + 3];
    c1b[0] = b1[16 + r4]; c1b[1] = b1[16 + r4 + 1]; c1b[2] = b1[16 + r4 + 2]; c1b[3] = b1[16 + r4 + 3];
    c2a[0] = b2[r4];      c2a[1] = b2[r4 + 1];      c2a[2] = b2[r4 + 2];      c2a[3] = b2[r4 + 3];
    c2b[0] = b2[16 + r4]; c2b[1] = b2[16 + r4 + 1]; c2b[2] = b2[16 + r4 + 2]; c2b[3] = b2[16 + r4 + 3];
    chd[0] = bmu[z2]; chd[1] = bmu[z2 + 1];   // head rows = [mu,mu,v,v]
    chd[2] = bv[z2];  chd[3] = bv[z2 + 1];

    f32x4 acc0 = {0.f, 0.f, 0.f, 0.f};   // [mu z2, mu z2+1, iv z2, iv z2+1] ch0
    f32x4 acc1 = {0.f, 0.f, 0.f, 0.f};   // same, ch1

    const float* bbase = batch + (size_t)b * 32 * (2 * N_);
    float* pA = &lds[wid][0][0];
    float* pB = &lds[wid][1][0];
    float* pC = &lds[wid][2][0];

    // prologue: iters 0,1,2 in flight; one barrier (sacc-init) drains them
    stage_wp(bbase, pA, 0, wid, l);
    stage_wp(bbase, pB, 1, wid, l);
    stage_wp(bbase, pC, 2, wid, l);
    __syncthreads();   // only block-wide sync before the tail

#pragma unroll 1
    for (int it = 0; it < NIT; ++it) {
        float* cur = pA;   // rotates A->B->C->A...

        // ---- this wave's 16 points x 2 channels from its private buffer ----
        float2 xr[8];
#pragma unroll
        for (int j = 0; j < 8; j++)
            xr[j] = *(const float2*)&cur[(kb * 8 + j) * 32 + c * 2];

        u32x4 w0, w1;
        w0[0] = cvtpk(xr[0].x, xr[1].x); w0[1] = cvtpk(xr[2].x, xr[3].x);
        w0[2] = cvtpk(xr[4].x, xr[5].x); w0[3] = cvtpk(xr[6].x, xr[7].x);
        w1[0] = cvtpk(xr[0].y, xr[1].y); w1[1] = cvtpk(xr[2].y, xr[3].y);
        w1[2] = cvtpk(xr[4].y, xr[5].y); w1[3] = cvtpk(xr[6].y, xr[7].y);
        const bf16x8 f0 = __builtin_bit_cast(bf16x8, w0);
        const bf16x8 f1 = __builtin_bit_cast(bf16x8, w1);

        // R15-proven fence: HARDWARE-complete this wave's LDS reads of cur
        // (lgkmcnt(0)) and PIN the DMA issue below them, before overwriting
        // cur with it+3 data (3-deep: issue target == compute source).
        asm volatile("s_waitcnt lgkmcnt(0)" ::: "memory");
        __builtin_amdgcn_sched_barrier(0);
        if (it + 3 < NIT)
            stage_wp(bbase, cur, it + 3, wid, l);
        __builtin_amdgcn_sched_barrier(0);

        f32x4 d1a0 = __builtin_amdgcn_mfma_f32_16x16x32_bf16(A1a, f0, c1a, 0, 0, 0);
        f32x4 d1b0 = __builtin_amdgcn_mfma_f32_16x16x32_bf16(A1b, f0, c1b, 0, 0, 0);
        f32x4 d1a1 = __builtin_amdgcn_mfma_f32_16x16x32_bf16(A1a, f1, c1a, 0, 0, 0);
        f32x4 d1b1 = __builtin_amdgcn_mfma_f32_16x16x32_bf16(A1b, f1, c1b, 0, 0, 0);

        bf16x8 p20 = pack_relu(d1a0, d1b0);
        bf16x8 p21 = pack_relu(d1a1, d1b1);

        f32x4 d2a0 = __builtin_amdgcn_mfma_f32_16x16x32_bf16(A2a, p20, c2a, 0, 0, 0);
        f32x4 d2b0 = __builtin_amdgcn_mfma_f32_16x16x32_bf16(A2b, p20, c2b, 0, 0, 0);
        f32x4 d2a1 = __builtin_amdgcn_mfma_f32_16x16x32_bf16(A2a, p21, c2a, 0, 0, 0);
        f32x4 d2b1 = __builtin_amdgcn_mfma_f32_16x16x32_bf16(A2b, p21, c2b, 0, 0, 0);

        bf16x8 p30 = pack_relu(d2a0, d2b0);
        bf16x8 p31 = pack_relu(d2a1, d2b1);

        f32x4 e0 = __builtin_amdgcn_mfma_f32_16x16x32_bf16(Ahd, p30, chd, 0, 0, 0);
        f32x4 e1 = __builtin_amdgcn_mfma_f32_16x16x32_bf16(Ahd, p31, chd, 0, 0, 0);

        // uniform head: every lane does 2 mu adds + 2 softplus chains per frag
        acc0[0] += e0[0];        acc0[1] += e0[1];
        acc0[2] += iv_of(e0[2]); acc0[3] += iv_of(e0[3]);
        acc1[0] += e1[0];        acc1[1] += e1[1];
        acc1[2] += iv_of(e1[2]); acc1[3] += iv_of(e1[3]);

        // counted per-wave wait: S(it+1) resident; S(it+2)+S(it+3) (8 loads)
        // stay in flight -> two adjacent 128B chunks per row concurrently
        // visible to the DRAM scheduler. Epilogue peels 8 -> 4 -> 0.
        if (it <= NIT - 4)
            asm volatile("s_waitcnt vmcnt(8)" ::: "memory");
        else if (it == NIT - 3)
            asm volatile("s_waitcnt vmcnt(4)" ::: "memory");
        else if (it == NIT - 2)
            asm volatile("s_waitcnt vmcnt(0)" ::: "memory");
        __builtin_amdgcn_sched_barrier(0);

        // rotate buffers A<-B<-C<-A
        float* t = pA; pA = pB; pB = pC; pC = t;
    }

    // ---- reduce over the 16 point-columns in each lane group ----
    red16(acc0);
    red16(acc1);

    if (c == 0) {
        // sacc: 0-7 mu ch0 | 8-15 mu ch1 | 16-23 iv ch0 | 24-31 iv ch1
        atomicAdd(&sacc[z2],          acc0[0]);
        atomicAdd(&sacc[z2 + 1],      acc0[1]);
        atomicAdd(&sacc[16 + z2],     acc0[2]);
        atomicAdd(&sacc[16 + z2 + 1], acc0[3]);
        atomicAdd(&sacc[8 + z2],      acc1[0]);
        atomicAdd(&sacc[8 + z2 + 1],  acc1[1]);
        atomicAdd(&sacc[24 + z2],     acc1[2]);
        atomicAdd(&sacc[24 + z2 + 1], acc1[3]);
    }
    __syncthreads();

    // ---- per-b tail on wave 0: pooling, KL, S x S sampled loss ----
    if (tid < 64) {
        const float a    = softplus_ref(sw[0]);
        const float sbv_ = sb[0];

        float muA[8], muB[8], sgA[8], sgB[8];
#pragma unroll
        for (int z = 0; z < 8; z++) {
            muA[z] = sacc[z];
            muB[z] = sacc[8 + z];
            sgA[z] = sqrtf(1.0f / sacc[16 + z]);
            sgB[z] = sqrtf(1.0f / sacc[24 + z]);
        }
        const int i = tid >> 3, j = tid & 7;
        float d2 = 0.f;
#pragma unroll
        for (int z = 0; z < 8; z++) {
            float e1 = eps1[((size_t)b * 8 + i) * 8 + z];
            float e2 = eps2[((size_t)b * 8 + j) * 8 + z];
            float zz1 = fmaf(sgA[z], e1, muA[z]);
            float zz2 = fmaf(sgB[z], e2, muB[z]);
            float d = zz1 - zz2;
            d2 = fmaf(d, d, d2);
        }
        const float lab = (float)labels[b];
        float contrib = softplus_ref(a * sqrtf(d2) - sbv_) * lab
                      * (1.0f / (64.0f * (float)B_));

        if (tid < 16) {
            const int cc = tid >> 3, z = tid & 7;
            float iv  = sacc[16 + cc * 8 + z];
            float var = 1.0f / iv;
            float m   = sacc[cc * 8 + z];
            contrib += (-0.5f * logf(var) + 0.5f * (var + m * m) - 0.5f)
                       * (BETA / (8.0f * (float)B_));
        }
#pragma unroll
        for (int off = 32; off; off >>= 1) contrib += __shfl_down(contrib, off);
        if (tid == 0) atomicAdd(out, contrib);
    }
}

extern "C" void kernel_launch(void* const* d_in, const int* in_sizes, int n_in,
                              void* d_out, int out_size, void* d_ws, size_t ws_size,
                              hipStream_t stream)
{
    (void)in_sizes; (void)n_in; (void)out_size; (void)ws_size;
    const float* batch  = (const float*)d_in[0];
    const int*   labels = (const int*)  d_in[1];
    const float* eps1   = (const float*)d_in[2];
    const float* eps2   = (const float*)d_in[3];
    const float* W1     = (const float*)d_in[4];
    const float* b1     = (const float*)d_in[5];
    const float* W2     = (const float*)d_in[6];
    const float* b2     = (const float*)d_in[7];
    const float* Wmu    = (const float*)d_in[8];
    const float* bmu    = (const float*)d_in[9];
    const float* Wv     = (const float*)d_in[10];
    const float* bv     = (const float*)d_in[11];
    const float* sw     = (const float*)d_in[12];
    const float* sb     = (const float*)d_in[13];

    unsigned short* wf = (unsigned short*)d_ws;  // 5 frags x 64 lanes x 8 bf16

    hipMemsetAsync(d_out, 0, sizeof(float), stream);
    hib_prep<<<1, 64, 0, stream>>>(W1, W2, Wmu, Wv, wf);
    hib_mfma<<<B_, 256, 0, stream>>>(batch, labels, eps1, eps2, wf,
                                     b1, b2, bmu, bv, sw, sb, (float*)d_out);
}

// Round 17
// 112.747 us; speedup vs baseline: 1.0122x; 1.0122x over previous
//
#include <hip/hip_runtime.h>
#include <hip/hip_bf16.h>

#define B_   2048
#define N_   1024
#define BETA 0.001f
#define VAR_MIN 1e-7f

#define NIT  16               // 16 iters x 16 pts = 256 pts per wave

typedef __attribute__((ext_vector_type(8))) short  bf16x8;
typedef __attribute__((ext_vector_type(4))) float  f32x4;
typedef __attribute__((ext_vector_type(4))) unsigned int u32x4;

__device__ __forceinline__ unsigned short f2bf_u(float x) {
    __hip_bfloat16 h = __float2bfloat16(x);   // RNE
    return __builtin_bit_cast(unsigned short, h);
}
__device__ __forceinline__ unsigned int cvtpk(float lo, float hi) {
    unsigned int r;
    asm("v_cvt_pk_bf16_f32 %0, %1, %2" : "=v"(r) : "v"(lo), "v"(hi));
    return r;
}
// hot-path softplus: 2 HW transcendentals. x<-16: 1+e^x -> 1 -> sp=0 -> VAR_MIN
// clamp, matching the reference's max(var, VAR_MIN).
__device__ __forceinline__ float softplus_cheap(float x) {
    float sp = __logf(1.f + __expf(x));
    return x > 15.f ? x : sp;
}
__device__ __forceinline__ float rcp_fast(float x) {
    return __builtin_amdgcn_rcpf(x);
}
__device__ __forceinline__ float softplus_ref(float x) {
    return x > 20.f ? x : log1pf(expf(x));
}
__device__ __forceinline__ float iv_of(float x) {
    return rcp_fast(fmaxf(softplus_cheap(x), VAR_MIN));
}

// pi(k): contraction-position permutation (verified absmax 0.0 in R4-R16)
__device__ __forceinline__ int kperm(int k) {
    return 4 * (k >> 3) + (k & 3) + 16 * ((k >> 2) & 1);
}

// A-frag weight prep; head rows interleaved [mu,mu,v,v] per lane-group (R13)
extern "C" __global__ void hib_prep(const float* __restrict__ W1,
                                    const float* __restrict__ W2,
                                    const float* __restrict__ Wmu,
                                    const float* __restrict__ Wv,
                                    unsigned short* __restrict__ wf)
{
    const int l = threadIdx.x;         // 0..63
    const int r = l & 15, kb = l >> 4;
    const int kbr = r >> 2, ri = r & 3;
#pragma unroll
    for (int j = 0; j < 8; j++) {
        const int k1 = kb * 8 + j;
        const int kp = kperm(k1);
        wf[(0 * 64 + l) * 8 + j] = f2bf_u(W1[k1 * 32 + r]);
        wf[(1 * 64 + l) * 8 + j] = f2bf_u(W1[k1 * 32 + 16 + r]);
        wf[(2 * 64 + l) * 8 + j] = f2bf_u(W2[kp * 32 + r]);
        wf[(3 * 64 + l) * 8 + j] = f2bf_u(W2[kp * 32 + 16 + r]);
        wf[(4 * 64 + l) * 8 + j] = f2bf_u(ri < 2 ? Wmu[kp * 8 + 2 * kbr + ri]
                                                 : Wv[kp * 8 + 2 * kbr + (ri - 2)]);
    }
}

__device__ __forceinline__ bf16x8 pack_relu(f32x4 a, f32x4 b) {
    u32x4 w;
    w[0] = cvtpk(fmaxf(a[0], 0.f), fmaxf(a[1], 0.f));
    w[1] = cvtpk(fmaxf(a[2], 0.f), fmaxf(a[3], 0.f));
    w[2] = cvtpk(fmaxf(b[0], 0.f), fmaxf(b[1], 0.f));
    w[3] = cvtpk(fmaxf(b[2], 0.f), fmaxf(b[3], 0.f));
    return __builtin_bit_cast(bf16x8, w);
}

__device__ __forceinline__ void red16(f32x4& v) {
#pragma unroll
    for (int off = 8; off; off >>= 1) {
        v[0] += __shfl_down(v[0], off);
        v[1] += __shfl_down(v[1], off);
        v[2] += __shfl_down(v[2], off);
        v[3] += __shfl_down(v[3], off);
    }
}

// wave-private stage: 32 rows x 16 pts x 2ch (4KB) for iteration `it`.
// 4 instrs; instr q: 8 rows x 128B, per-lane global addr (row l>>3, 16B chunk
// l&7), wave-uniform LDS dest (linear lane*16B = [row][ptpair] layout).
__device__ __forceinline__ void stage_wp(const float* __restrict__ bbase,
                                         float* __restrict__ buf,
                                         int it, int wid, int l)
{
    const int lrow = l >> 3, lcol = (l & 7) * 4;   // floats
    const int colbase = (wid * 256 + it * 16) * 2; // floats within a row
#pragma unroll
    for (int q = 0; q < 4; ++q) {
        const int row = q * 8 + lrow;
        const float* gs = bbase + (size_t)row * (2 * N_) + colbase + lcol;
        __builtin_amdgcn_global_load_lds(
            (const __attribute__((address_space(1))) unsigned int*)gs,
            (__attribute__((address_space(3))) unsigned int*)&buf[q * 8 * 32],
            16, 0, 0);
    }
}

__global__ void __launch_bounds__(256, 4)
hib_mfma(const float* __restrict__ batch,
         const int* __restrict__ labels,
         const float* __restrict__ eps1, const float* __restrict__ eps2,
         const unsigned short* __restrict__ wf,
         const float* __restrict__ b1, const float* __restrict__ b2,
         const float* __restrict__ bmu, const float* __restrict__ bv,
         const float* __restrict__ sw, const float* __restrict__ sb,
         float* __restrict__ out)
{
    __shared__ float lds[4][2][32 * 32];   // [wave][buf][row*32] = 32KB
    __shared__ float sacc[32];

    const int tid = threadIdx.x;
    const int b   = blockIdx.x;
    const int wid = tid >> 6, l = tid & 63;
    const int c   = l & 15, kb = l >> 4;

    if (tid < 32) sacc[tid] = 0.f;

    // weight A-frags, register-resident
    const bf16x8* wfv = (const bf16x8*)wf;
    const bf16x8 A1a = wfv[0 * 64 + l], A1b = wfv[1 * 64 + l];
    const bf16x8 A2a = wfv[2 * 64 + l], A2b = wfv[3 * 64 + l];
    const bf16x8 Ahd = wfv[4 * 64 + l];

    const int r4 = 4 * kb;
    const int z2 = 2 * kb;          // interleaved head: this group's z-pair
    f32x4 c1a, c1b, c2a, c2b, chd;
    c1a[0] = b1[r4];      c1a[1] = b1[r4 + 1];      c1a[2] = b1[r4 + 2];      c1a[3] = b1[r4 + 3];
    c1b[0] = b1[16 + r4]; c1b[1] = b1[16 + r4 + 1]; c1b[2] = b1[16 + r4 + 2]; c1b[3] = b1[16 + r4 + 3];
    c2a[0] = b2[r4];      c2a[1] = b2[r4 + 1];      c2a[2] = b2[r4 + 2];      c2a[3] = b2[r4 + 3];
    c2b[0] = b2[16 + r4]; c2b[1] = b2[16 + r4 + 1]; c2b[2] = b2[16 + r4 + 2]; c2b[3] = b2[16 + r4 + 3];
    chd[0] = bmu[z2]; chd[1] = bmu[z2 + 1];   // head rows = [mu,mu,v,v]
    chd[2] = bv[z2];  chd[3] = bv[z2 + 1];

    f32x4 acc0 = {0.f, 0.f, 0.f, 0.f};   // [mu z2, mu z2+1, iv z2, iv z2+1] ch0
    f32x4 acc1 = {0.f, 0.f, 0.f, 0.f};   // same, ch1

    const float* bbase = batch + (size_t)b * 32 * (2 * N_);
    float* bufA = &lds[wid][0][0];
    float* bufB = &lds[wid][1][0];

    // prologue: iters 0,1 in flight; one barrier (sacc-init visibility) drains
    stage_wp(bbase, bufA, 0, wid, l);
    stage_wp(bbase, bufB, 1, wid, l);
    __syncthreads();   // only block-wide sync before the tail

#pragma unroll 1
    for (int it = 0; it < NIT; ++it) {
        float* cur = (it & 1) ? bufB : bufA;

        // ---- this wave's 16 points x 2 channels from its private buffer ----
        float2 xr[8];
#pragma unroll
        for (int j = 0; j < 8; j++)
            xr[j] = *(const float2*)&cur[(kb * 8 + j) * 32 + c * 2];

        u32x4 w0, w1;
        w0[0] = cvtpk(xr[0].x, xr[1].x); w0[1] = cvtpk(xr[2].x, xr[3].x);
        w0[2] = cvtpk(xr[4].x, xr[5].x); w0[3] = cvtpk(xr[6].x, xr[7].x);
        w1[0] = cvtpk(xr[0].y, xr[1].y); w1[1] = cvtpk(xr[2].y, xr[3].y);
        w1[2] = cvtpk(xr[4].y, xr[5].y); w1[3] = cvtpk(xr[6].y, xr[7].y);
        const bf16x8 f0 = __builtin_bit_cast(bf16x8, w0);
        const bf16x8 f1 = __builtin_bit_cast(bf16x8, w1);

        // R15-proven fence: HARDWARE-complete this wave's LDS reads of cur
        // (lgkmcnt(0)), and PIN the DMA issue below them (sched_barrier),
        // before overwriting cur with it+2 data. Source order alone is not
        // a guarantee (rule #18 class: compiler may not see the builtin's
        // LDS write as aliasing the ds_reads).
        asm volatile("s_waitcnt lgkmcnt(0)" ::: "memory");
        __builtin_amdgcn_sched_barrier(0);
        if (it + 2 < NIT)
            stage_wp(bbase, cur, it + 2, wid, l);
        __builtin_amdgcn_sched_barrier(0);

        f32x4 d1a0 = __builtin_amdgcn_mfma_f32_16x16x32_bf16(A1a, f0, c1a, 0, 0, 0);
        f32x4 d1b0 = __builtin_amdgcn_mfma_f32_16x16x32_bf16(A1b, f0, c1b, 0, 0, 0);
        f32x4 d1a1 = __builtin_amdgcn_mfma_f32_16x16x32_bf16(A1a, f1, c1a, 0, 0, 0);
        f32x4 d1b1 = __builtin_amdgcn_mfma_f32_16x16x32_bf16(A1b, f1, c1b, 0, 0, 0);

        bf16x8 p20 = pack_relu(d1a0, d1b0);
        bf16x8 p21 = pack_relu(d1a1, d1b1);

        f32x4 d2a0 = __builtin_amdgcn_mfma_f32_16x16x32_bf16(A2a, p20, c2a, 0, 0, 0);
        f32x4 d2b0 = __builtin_amdgcn_mfma_f32_16x16x32_bf16(A2b, p20, c2b, 0, 0, 0);
        f32x4 d2a1 = __builtin_amdgcn_mfma_f32_16x16x32_bf16(A2a, p21, c2a, 0, 0, 0);
        f32x4 d2b1 = __builtin_amdgcn_mfma_f32_16x16x32_bf16(A2b, p21, c2b, 0, 0, 0);

        bf16x8 p30 = pack_relu(d2a0, d2b0);
        bf16x8 p31 = pack_relu(d2a1, d2b1);

        f32x4 e0 = __builtin_amdgcn_mfma_f32_16x16x32_bf16(Ahd, p30, chd, 0, 0, 0);
        f32x4 e1 = __builtin_amdgcn_mfma_f32_16x16x32_bf16(Ahd, p31, chd, 0, 0, 0);

        // uniform head: every lane does 2 mu adds + 2 softplus chains per frag
        acc0[0] += e0[0];        acc0[1] += e0[1];
        acc0[2] += iv_of(e0[2]); acc0[3] += iv_of(e0[3]);
        acc1[0] += e1[0];        acc1[1] += e1[1];
        acc1[2] += iv_of(e1[2]); acc1[3] += iv_of(e1[3]);

        // per-wave counted wait: next iter's batch resident, the batch just
        // issued (it+2) stays in flight. No block barrier.
        if (it < NIT - 2)
            asm volatile("s_waitcnt vmcnt(4)" ::: "memory");
        else if (it == NIT - 2)
            asm volatile("s_waitcnt vmcnt(0)" ::: "memory");
        __builtin_amdgcn_sched_barrier(0);
    }

    // ---- reduce over the 16 point-columns in each lane group ----
    red16(acc0);
    red16(acc1);

    if (c == 0) {
        // sacc: 0-7 mu ch0 | 8-15 mu ch1 | 16-23 iv ch0 | 24-31 iv ch1
        atomicAdd(&sacc[z2],          acc0[0]);
        atomicAdd(&sacc[z2 + 1],      acc0[1]);
        atomicAdd(&sacc[16 + z2],     acc0[2]);
        atomicAdd(&sacc[16 + z2 + 1], acc0[3]);
        atomicAdd(&sacc[8 + z2],      acc1[0]);
        atomicAdd(&sacc[8 + z2 + 1],  acc1[1]);
        atomicAdd(&sacc[24 + z2],     acc1[2]);
        atomicAdd(&sacc[24 + z2 + 1], acc1[3]);
    }
    __syncthreads();

    // ---- per-b tail on wave 0: pooling, KL, S x S sampled loss ----
    if (tid < 64) {
        const float a    = softplus_ref(sw[0]);
        const float sbv_ = sb[0];

        float muA[8], muB[8], sgA[8], sgB[8];
#pragma unroll
        for (int z = 0; z < 8; z++) {
            muA[z] = sacc[z];
            muB[z] = sacc[8 + z];
            sgA[z] = sqrtf(1.0f / sacc[16 + z]);
            sgB[z] = sqrtf(1.0f / sacc[24 + z]);
        }
        const int i = tid >> 3, j = tid & 7;
        float d2 = 0.f;
#pragma unroll
        for (int z = 0; z < 8; z++) {
            float e1 = eps1[((size_t)b * 8 + i) * 8 + z];
            float e2 = eps2[((size_t)b * 8 + j) * 8 + z];
            float zz1 = fmaf(sgA[z], e1, muA[z]);
            float zz2 = fmaf(sgB[z], e2, muB[z]);
            float d = zz1 - zz2;
            d2 = fmaf(d, d, d2);
        }
        const float lab = (float)labels[b];
        float contrib = softplus_ref(a * sqrtf(d2) - sbv_) * lab
                      * (1.0f / (64.0f * (float)B_));

        if (tid < 16) {
            const int cc = tid >> 3, z = tid & 7;
            float iv  = sacc[16 + cc * 8 + z];
            float var = 1.0f / iv;
            float m   = sacc[cc * 8 + z];
            contrib += (-0.5f * logf(var) + 0.5f * (var + m * m) - 0.5f)
                       * (BETA / (8.0f * (float)B_));
        }
#pragma unroll
        for (int off = 32; off; off >>= 1) contrib += __shfl_down(contrib, off);
        if (tid == 0) atomicAdd(out, contrib);
    }
}

extern "C" void kernel_launch(void* const* d_in, const int* in_sizes, int n_in,
                              void* d_out, int out_size, void* d_ws, size_t ws_size,
                              hipStream_t stream)
{
    (void)in_sizes; (void)n_in; (void)out_size; (void)ws_size;
    const float* batch  = (const float*)d_in[0];
    const int*   labels = (const int*)  d_in[1];
    const float* eps1   = (const float*)d_in[2];
    const float* eps2   = (const float*)d_in[3];
    const float* W1     = (const float*)d_in[4];
    const float* b1     = (const float*)d_in[5];
    const float* W2     = (const float*)d_in[6];
    const float* b2     = (const float*)d_in[7];
    const float* Wmu    = (const float*)d_in[8];
    const float* bmu    = (const float*)d_in[9];
    const float* Wv     = (const float*)d_in[10];
    const float* bv     = (const float*)d_in[11];
    const float* sw     = (const float*)d_in[12];
    const float* sb     = (const float*)d_in[13];

    unsigned short* wf = (unsigned short*)d_ws;  // 5 frags x 64 lanes x 8 bf16

    hipMemsetAsync(d_out, 0, sizeof(float), stream);
    hib_prep<<<1, 64, 0, stream>>>(W1, W2, Wmu, Wv, wf);
    hib_mfma<<<B_, 256, 0, stream>>>(batch, labels, eps1, eps2, wf,
                                     b1, b2, bmu, bv, sw, sb, (float*)d_out);
}